// Round 1
// 254.605 us; speedup vs baseline: 1.0463x; 1.0463x over previous
//
#include <hip/hip_runtime.h>
#include <math.h>

#define NEG_SLOPE 0.2f
#define NBUK_MAX 512    // LDS capacity for bucket counters (buckets of 256 dsts; NBUK=391, must be <=512)

typedef float v4f __attribute__((ext_vector_type(4)));
typedef _Float16 h4v __attribute__((ext_vector_type(4)));   // 8B: 4 packed fp16 features

// ---------------- K_A: histB (blocks 0..B2) UNION argmax (rest) ----------------
// bucket = dst >> 8 (256 dsts per bucket)
template <int B2>
__global__ void __launch_bounds__(1024)
k_histarg(const float* __restrict__ x, const int* __restrict__ edst, int E,
          int* __restrict__ histT, int NBUK, int* __restrict__ idx, int N, int V) {
    __shared__ int sh[NBUK_MAX];
    int t = threadIdx.x;
    if ((int)blockIdx.x < B2) {
        int b = blockIdx.x;
        for (int k = t; k < NBUK; k += 1024) sh[k] = 0;
        __syncthreads();
        long long ebeg = (long long)b * E / B2, eend = (long long)(b + 1) * E / B2;
        for (long long i = ebeg + t; i < eend; i += 1024)
            atomicAdd(&sh[edst[i] >> 8], 1);
        __syncthreads();
        for (int k = t; k < NBUK; k += 1024) histT[(long long)k * B2 + b] = sh[k];
    } else {
        int node = ((int)blockIdx.x - B2) * 32 + (t >> 5);
        int lane = t & 31;
        if (node >= N) return;
        const v4f* row = (const v4f*)(x + (long long)node * V);
        float bv = -INFINITY;
        int bi = 0x7fffffff;
        int nq = V >> 2;
        for (int q = lane; q < nq; q += 32) {
            v4f v = row[q];
            int base = q << 2;
            if (v.x > bv || (v.x == bv && base     < bi)) { bv = v.x; bi = base;     }
            if (v.y > bv || (v.y == bv && base + 1 < bi)) { bv = v.y; bi = base + 1; }
            if (v.z > bv || (v.z == bv && base + 2 < bi)) { bv = v.z; bi = base + 2; }
            if (v.w > bv || (v.w == bv && base + 3 < bi)) { bv = v.w; bi = base + 3; }
        }
        for (int off = 16; off > 0; off >>= 1) {
            float ov = __shfl_down(bv, off, 32);
            int   oi = __shfl_down(bi, off, 32);
            if (ov > bv || (ov == bv && oi < bi)) { bv = ov; bi = oi; }
        }
        if (lane == 0) idx[node] = bi;
    }
}

// ---------------- K_B: scan1 (blocks 0..NB_SCAN) UNION layer-1 transform (rest) ----------------
template <int FIN, int FOUT>
__global__ void __launch_bounds__(256)
k_scan_tr(const int* __restrict__ vals, int* __restrict__ excl, int* __restrict__ bsums, int M,
          const float* __restrict__ emb, const int* __restrict__ idx,
          const float* __restrict__ W, const float* __restrict__ a_src,
          const float* __restrict__ a_dst, _Float16* __restrict__ h_t,
          float* __restrict__ asrc, float* __restrict__ adst, int N, int NB_SCAN) {
    __shared__ int s[256];
    __shared__ float sW[FIN * FOUT];
    __shared__ float sa[FOUT], sd[FOUT];
    int t = threadIdx.x;
    if ((int)blockIdx.x < NB_SCAN) {
        int i = blockIdx.x * 256 + t;
        int v = (i < M) ? vals[i] : 0;
        s[t] = v;
        __syncthreads();
        for (int off = 1; off < 256; off <<= 1) {
            int a = (t >= off) ? s[t - off] : 0;
            __syncthreads();
            s[t] += a;
            __syncthreads();
        }
        if (i < M) excl[i] = s[t] - v;
        if (t == 255) bsums[blockIdx.x] = s[255];   // raw chunk sums (scanned locally by consumers)
    } else {
        for (int i = t; i < FIN * FOUT; i += 256) sW[i] = W[i];
        if (t < FOUT) { sa[t] = a_src[t]; sd[t] = a_dst[t]; }
        __syncthreads();
        int n = ((int)blockIdx.x - NB_SCAN) * 256 + t;
        if (n >= N) return;
        float acc[FOUT];
#pragma unroll
        for (int f = 0; f < FOUT; f++) acc[f] = 0.f;
        const float* hr = emb + (long long)idx[n] * FIN;
        for (int k = 0; k < FIN; k++) {
            float v = hr[k];
#pragma unroll
            for (int f = 0; f < FOUT; f++) acc[f] += v * sW[k * FOUT + f];
        }
        float s1 = 0.f, s2 = 0.f;
        _Float16 hh[16];
#pragma unroll
        for (int f = 0; f < 16; f++) hh[f] = (_Float16)0.f;
#pragma unroll
        for (int f = 0; f < FOUT; f++) {
            hh[f] = (_Float16)acc[f];
            s1 += acc[f] * sa[f];
            s2 += acc[f] * sd[f];
        }
        uint4* dst = (uint4*)(h_t + (long long)n * 16);
        dst[0] = ((uint4*)hh)[0];
        dst[1] = ((uint4*)hh)[1];
        asrc[n] = s1;
        adst[n] = s2;
    }
}

// ---------------- scatB: exact-slot scatter; LDS cursors; local 391-scan of bsums ----------------
// B2=256: one scan chunk per bucket -> soff(k,b) = sexcl[k*B2+b] + bexcl[k]
template <int B2>
__global__ void __launch_bounds__(1024)
k_scatB(const int* __restrict__ esrc, const int* __restrict__ edst, int E,
        const int* __restrict__ sexcl, const int* __restrict__ bsums,
        int* __restrict__ tmp, int NBUK) {
    __shared__ int cur[NBUK_MAX];
    __shared__ int bex[512];
    int t = threadIdx.x, b = blockIdx.x;
    if (t < 512) bex[t] = (t < NBUK) ? bsums[t] : 0;
    __syncthreads();
    for (int off = 1; off < 512; off <<= 1) {            // inclusive scan, 512 wide
        int a = (t < 512 && t >= off) ? bex[t - off] : 0;
        __syncthreads();
        if (t < 512) bex[t] += a;
        __syncthreads();
    }
    for (int k = t; k < NBUK; k += 1024)
        cur[k] = sexcl[(long long)k * B2 + b] + (k ? bex[k - 1] : 0);
    __syncthreads();
    long long ebeg = (long long)b * E / B2, eend = (long long)(b + 1) * E / B2;
    for (long long i = ebeg + t; i < eend; i += 1024) {
        int d = edst[i];
        int pos = atomicAdd(&cur[d >> 8], 1);
        tmp[pos] = ((d & 255) << 17) | esrc[i];   // src < 2^17
    }
}

// ---------------- binB: 256-dst buckets; local 391-scan; bin to exact csr slots ----------------
template <int B2>
__global__ void __launch_bounds__(256)
k_binB(const int* __restrict__ sexcl, const int* __restrict__ bsums,
       const int* __restrict__ tmp,
       int* __restrict__ rowptr, int* __restrict__ csr_src, int N, int NBUK, int E) {
    __shared__ int bx[512];
    __shared__ int cnt[256];
    __shared__ int scn[256];
    __shared__ int cur[256];
    int t = threadIdx.x, b = blockIdx.x;
    bx[t]       = (t < NBUK)       ? bsums[t]       : 0;
    bx[t + 256] = (t + 256 < NBUK) ? bsums[t + 256] : 0;
    __syncthreads();
    for (int off = 1; off < 512; off <<= 1) {            // inclusive scan, 2 elems/thread
        int a0 = (t >= off) ? bx[t - off] : 0;
        int a1 = (t + 256 >= off) ? bx[t + 256 - off] : 0;
        __syncthreads();
        bx[t] += a0;
        bx[t + 256] += a1;
        __syncthreads();
    }
    int t0 = sexcl[(long long)b * B2] + (b ? bx[b - 1] : 0);
    int t1 = (b + 1 < NBUK) ? (sexcl[(long long)(b + 1) * B2] + bx[b]) : E;
    cnt[t] = 0;
    __syncthreads();
    for (int i = t0 + t; i < t1; i += 256) atomicAdd(&cnt[tmp[i] >> 17], 1);
    __syncthreads();
    int v = cnt[t];
    scn[t] = v;
    __syncthreads();
    for (int off = 1; off < 256; off <<= 1) {
        int a = (t >= off) ? scn[t - off] : 0;
        __syncthreads();
        scn[t] += a;
        __syncthreads();
    }
    int base = t0 + scn[t] - v;
    int d = (b << 8) + t;
    if (d < N) rowptr[d] = base;
    cur[t] = base;
    if (d == N - 1) rowptr[N] = E;
    __syncthreads();
    for (int i = t0 + t; i < t1; i += 256) {
        int p = tmp[i];
        int pos = atomicAdd(&cur[p >> 17], 1);
        csr_src[pos] = p & 0x1FFFF;
    }
}

// ---------------- GAT aggregation core: 4-lane groups, lane = 4 packed f16 features ----------------
// One shfl pair serves 16 dsts/wave (vs 4 with 16-lane groups): 4x fewer DS ops per edge.
template <typename EPI>
__device__ __forceinline__ void gat_core4(const int* __restrict__ rowptr,
                                          const int* __restrict__ csr_src,
                                          const float* __restrict__ asrc,
                                          const float* __restrict__ adst,
                                          const _Float16* __restrict__ h_t,
                                          int d, int l4, EPI epilogue) {
    const h4v* __restrict__ H = (const h4v*)h_t;       // row d = H[d*4 .. d*4+3]
    int r0 = rowptr[d], r1 = rowptr[d + 1];
    float ad = adst[d];

    // self loop
    float e0 = asrc[d] + ad;
    e0 = (e0 >= 0.f) ? e0 : NEG_SLOPE * e0;
    float p0 = __expf(e0);
    h4v hd = H[(long long)d * 4 + l4];
    float a0 = p0 * (float)hd[0], a1 = p0 * (float)hd[1];
    float a2 = p0 * (float)hd[2], a3 = p0 * (float)hd[3];
    float psum = (l4 == 0) ? p0 : 0.f;

    int rem = r1 - r0;
    if (rem > 0) {
        int j = r0;
        int s = (l4 < rem) ? csr_src[j + l4] : d;
        float av = asrc[s];
        while (true) {
            int remn = rem - 4;
            int s2 = d; float av2 = 0.f;
            if (remn > 0) {                               // prefetch next chunk
                s2 = (l4 < remn) ? csr_src[j + 4 + l4] : d;
                av2 = asrc[s2];
            }
            float e = av + ad;
            e = (e >= 0.f) ? e : NEG_SLOPE * e;
            float p = (l4 < rem) ? __expf(e) : 0.f;
            psum += p;
#pragma unroll
            for (int k = 0; k < 4; k++) {
                float pk = __shfl(p, k, 4);
                int   sk = __shfl(s, k, 4);
                h4v hh = H[(long long)sk * 4 + l4];
                a0 += pk * (float)hh[0];
                a1 += pk * (float)hh[1];
                a2 += pk * (float)hh[2];
                a3 += pk * (float)hh[3];
            }
            if (remn <= 0) break;
            j += 4; rem = remn; s = s2; av = av2;
        }
    }
    psum += __shfl_xor(psum, 1, 4);
    psum += __shfl_xor(psum, 2, 4);
    float inv = 1.f / fmaxf(psum, 1e-16f);
    epilogue(d, a0 * inv, a1 * inv, a2 * inv, a3 * inv);
}

// gat + bias/relu + NEXT-layer transform fused in-register (4-lane groups)
// sW padded to stride 16 with zero-fill -> no FN masking needed anywhere.
template <int FN>
__global__ void __launch_bounds__(256)
k_gat_ft(const int* __restrict__ rowptr, const int* __restrict__ csr_src,
         const float* __restrict__ asrc, const float* __restrict__ adst,
         const _Float16* __restrict__ h_t, const float* __restrict__ bias,
         const float* __restrict__ Wn, const float* __restrict__ an_src,
         const float* __restrict__ an_dst,
         _Float16* __restrict__ h_next, float* __restrict__ asrc_n,
         float* __restrict__ adst_n, int N) {
    __shared__ float sW[16 * 16];
    __shared__ float sa[16], sd[16], sb[16];
    int t = threadIdx.x;
    {
        int k = t >> 4, f = t & 15;
        sW[t] = (f < FN) ? Wn[k * FN + f] : 0.f;
    }
    if (t < 16) {
        sa[t] = (t < FN) ? an_src[t] : 0.f;
        sd[t] = (t < FN) ? an_dst[t] : 0.f;
        sb[t] = bias[t];
    }
    __syncthreads();

    int gid = blockIdx.x * 256 + t;
    int d = gid >> 2, l4 = gid & 3;
    if (d >= N) return;

    gat_core4(rowptr, csr_src, asrc, adst, h_t, d, l4,
        [&](int dd, float v0, float v1, float v2, float v3) {
            int f0 = l4 * 4;
            float vv[4];
            vv[0] = fmaxf(v0 + sb[f0    ], 0.f);
            vv[1] = fmaxf(v1 + sb[f0 + 1], 0.f);
            vv[2] = fmaxf(v2 + sb[f0 + 2], 0.f);
            vv[3] = fmaxf(v3 + sb[f0 + 3], 0.f);
            float o0 = 0.f, o1 = 0.f, o2 = 0.f, o3 = 0.f;
#pragma unroll
            for (int q = 0; q < 4; q++) {
#pragma unroll
                for (int i = 0; i < 4; i++) {
                    float vk = __shfl(vv[i], q, 4);      // broadcast feature k=q*4+i of dst
                    const float* wr = &sW[(q * 4 + i) * 16 + f0];
                    o0 += vk * wr[0];
                    o1 += vk * wr[1];
                    o2 += vk * wr[2];
                    o3 += vk * wr[3];
                }
            }
            float c1 = o0 * sa[f0] + o1 * sa[f0 + 1] + o2 * sa[f0 + 2] + o3 * sa[f0 + 3];
            float c2 = o0 * sd[f0] + o1 * sd[f0 + 1] + o2 * sd[f0 + 2] + o3 * sd[f0 + 3];
            c1 += __shfl_xor(c1, 1, 4); c1 += __shfl_xor(c1, 2, 4);
            c2 += __shfl_xor(c2, 1, 4); c2 += __shfl_xor(c2, 2, 4);
            h4v ho = { (_Float16)o0, (_Float16)o1, (_Float16)o2, (_Float16)o3 };
            ((h4v*)h_next)[(long long)dd * 4 + l4] = ho;
            if (l4 == 0) { asrc_n[dd] = c1; adst_n[dd] = c2; }
        });
}

// final gat: fp32 out rows padded to stride 16 (aligned float4 stores; cols >=10 are zero)
__global__ void __launch_bounds__(256)
k_gat_last(const int* __restrict__ rowptr, const int* __restrict__ csr_src,
           const float* __restrict__ asrc, const float* __restrict__ adst,
           const _Float16* __restrict__ h_t, float* __restrict__ out, int N) {
    int gid = blockIdx.x * 256 + threadIdx.x;
    int d = gid >> 2, l4 = gid & 3;
    if (d >= N) return;
    gat_core4(rowptr, csr_src, asrc, adst, h_t, d, l4,
        [&](int dd, float v0, float v1, float v2, float v3) {
            v4f o = { v0, v1, v2, v3 };
            ((v4f*)out)[(long long)dd * 4 + l4] = o;
        });
}

// ---------------- pool + softmax (h3 rows have stride 16) ----------------
__global__ void k_pool(const float* __restrict__ h3, const int* __restrict__ batch,
                       const float* __restrict__ b3, float* __restrict__ out, int N, int C) {
    int g = blockIdx.x;
    int lo = 0, hi = N;
    while (lo < hi) { int mid = (lo + hi) >> 1; if (batch[mid] < g) lo = mid + 1; else hi = mid; }
    int start = lo;
    hi = N;
    while (lo < hi) { int mid = (lo + hi) >> 1; if (batch[mid] < g + 1) lo = mid + 1; else hi = mid; }
    int end = lo;

    float sum[16];
    for (int f = 0; f < C; f++) sum[f] = 0.f;
    for (int n = start + threadIdx.x; n < end; n += blockDim.x) {
        const float* r = h3 + (long long)n * 16;
        for (int f = 0; f < C; f++) sum[f] += r[f];
    }
    __shared__ float red[256 * 16];
    for (int f = 0; f < C; f++) red[threadIdx.x * 16 + f] = sum[f];
    __syncthreads();
    for (int str = blockDim.x / 2; str > 0; str >>= 1) {
        if ((int)threadIdx.x < str)
            for (int f = 0; f < C; f++) red[threadIdx.x * 16 + f] += red[(threadIdx.x + str) * 16 + f];
        __syncthreads();
    }
    if (threadIdx.x == 0) {
        float cnt = fmaxf((float)(end - start), 1.f);
        float vals[16];
        float mx = -INFINITY;
        for (int f = 0; f < C; f++) { vals[f] = red[f] / cnt + b3[f]; mx = fmaxf(mx, vals[f]); }
        float se = 0.f;
        for (int f = 0; f < C; f++) { vals[f] = __expf(vals[f] - mx); se += vals[f]; }
        for (int f = 0; f < C; f++) out[(long long)g * C + f] = vals[f] / se;
    }
}

extern "C" void kernel_launch(void* const* d_in, const int* in_sizes, int n_in,
                              void* d_out, int out_size, void* d_ws, size_t ws_size,
                              hipStream_t stream) {
    const float* x    = (const float*)d_in[0];
    const int*   eidx = (const int*)d_in[1];
    const int*   batch= (const int*)d_in[2];
    const float* emb  = (const float*)d_in[3];
    const float* W1   = (const float*)d_in[4];
    const float* as1  = (const float*)d_in[5];
    const float* ad1  = (const float*)d_in[6];
    const float* b1   = (const float*)d_in[7];
    const float* W2   = (const float*)d_in[8];
    const float* as2  = (const float*)d_in[9];
    const float* ad2  = (const float*)d_in[10];
    const float* b2   = (const float*)d_in[11];
    const float* W3   = (const float*)d_in[12];
    const float* as3  = (const float*)d_in[13];
    const float* ad3  = (const float*)d_in[14];
    const float* b3   = (const float*)d_in[15];

    const int H = in_sizes[5];          // 16
    const int C = in_sizes[13];         // 10
    const int D = in_sizes[4] / H;      // 50
    const int V = in_sizes[3] / D;      // 128
    const int N = in_sizes[0] / V;      // 100000
    const int E = in_sizes[1] / 2;      // 1600000
    const int G = out_size / C;         // 512
    const int* esrc = eidx;
    const int* edst = eidx + E;
    const int NBUK = (N + 255) >> 8;    // 391 buckets of 256 dsts (must be <=512)
    constexpr int B2 = 256;             // scatter blocks; runs ~16 entries = one 64B line
    const int M = NBUK * B2;            // histT elements (100K)

    char* w = (char*)d_ws;
    auto carve = [&](size_t bytes) {
        char* p = w;
        w += (bytes + 255) & ~(size_t)255;
        return p;
    };
    float*     as_a    = (float*)carve((size_t)N * 4);
    float*     ad_a    = (float*)carve((size_t)N * 4);
    float*     as_b    = (float*)carve((size_t)N * 4);
    float*     ad_b    = (float*)carve((size_t)N * 4);
    int*       idx     = (int*)carve((size_t)N * 4);
    int*       rowptr  = (int*)carve((size_t)(N + 1) * 4);
    int*       csr_src = (int*)carve((size_t)E * 4);
    int*       histT   = (int*)carve((size_t)M * 4);
    int*       sexcl   = (int*)carve((size_t)M * 4);
    int*       bsums   = (int*)carve(2048 * 4);
    _Float16*  hTa     = (_Float16*)carve((size_t)N * 16 * 2);
    _Float16*  hTb     = (_Float16*)carve((size_t)N * 16 * 2);
    size_t zone_bytes = ((size_t)E * 4 > (size_t)N * 64) ? (size_t)E * 4 : (size_t)N * 64;
    char*  zone = carve(zone_bytes);
    float* X0  = (float*)zone;          // N x 16 fp32 (padded rows)
    int*   tmp = (int*)zone;
    (void)ws_size; (void)n_in;

    const int BT = 256;
    dim3 blk(BT);
    int gGat4 = (N * 4 + BT - 1) / BT;      // 4 lanes per dst
    int nb2   = (M + 255) / 256;            // scan blocks over histT (391)
    int gArg  = (N + 31) / 32;              // argmax blocks (32 nodes per 1024-thr block)
    int gTr   = (N + BT - 1) / BT;          // transform blocks

    // ---- K_A: histB + argmax in one launch ----
    k_histarg<B2><<<B2 + gArg, dim3(1024), 0, stream>>>(x, edst, E, histT, NBUK, idx, N, V);

    // ---- K_B: scan1 + layer-1 transform in one launch (bsums stay raw chunk sums) ----
    k_scan_tr<50, 16><<<nb2 + gTr, blk, 0, stream>>>(histT, sexcl, bsums, M,
                                                     emb, idx, W1, as1, ad1, hTa, as_a, ad_a, N, nb2);

    // ---- scatter + bin (each does its own 391-wide scan of bsums in LDS) ----
    k_scatB<B2><<<B2, dim3(1024), 0, stream>>>(esrc, edst, E, sexcl, bsums, tmp, NBUK);
    k_binB<B2><<<NBUK, blk, 0, stream>>>(sexcl, bsums, tmp, rowptr, csr_src, N, NBUK, E);

    // ---- gat1 (+b1,relu) fused with transform2 -> hTb, a_b ----
    k_gat_ft<16><<<gGat4, blk, 0, stream>>>(rowptr, csr_src, as_a, ad_a, hTa, b1,
                                            W2, as2, ad2, hTb, as_b, ad_b, N);

    // ---- gat2 (+b2,relu) fused with transform3 -> hTa, a_a ----
    k_gat_ft<10><<<gGat4, blk, 0, stream>>>(rowptr, csr_src, as_b, ad_b, hTb, b2,
                                            W3, as3, ad3, hTa, as_a, ad_a, N);

    // ---- gat3 -> X0 (N x 16 fp32, cols >=10 zero) ----
    k_gat_last<<<gGat4, blk, 0, stream>>>(rowptr, csr_src, as_a, ad_a, hTa, X0, N);

    // ---- pool + softmax ----
    k_pool<<<G, blk, 0, stream>>>(X0, batch, b3, (float*)d_out, N, C);
}